// Round 8
// baseline (490.489 us; speedup 1.0000x reference)
//
#include <hip/hip_runtime.h>
#include <math.h>

// EncoderBlock: B=8, N=1024, EMB=768, HEADS=8, DHEAD=96
// R16 = R15 with the GEMM engine switched 16x16x32 -> 32x32x16 MFMA:
//   - disambiguates the ~16cy/MFMA-instruction plateau: per wave-K-tile the
//     instruction count halves (32->16) at IDENTICAL LDS read traffic
//     (16 x ds_read_b128 either way). If per-instruction-bound -> ~2x tile
//     speedup; if traffic-bound -> null (then next round targets attn).
//   - k-major LDS layout [k-unit][row]: staging is linear (no XOR swizzle),
//     frag reads = base VGPR + compile-time offset, lanes 0-31 read 512
//     contiguous bytes -> conflict-free.
//   - macro-schedule unchanged from R12/R15: 256x128 tile, BK=64, 8 waves
//     4(M)x2(N), triple-buffered 144KiB LDS, single barrier + single
//     vmcnt(6) per K-tile, same prologue/tail, same grids & epilogues.
//   prep fusion / vectorized LN / attention: unchanged from R15 (358.1us).

typedef __bf16 bf16_t;
typedef __bf16 bf16x4 __attribute__((ext_vector_type(4)));
typedef __bf16 bf16x8 __attribute__((ext_vector_type(8)));
typedef float f32x4 __attribute__((ext_vector_type(4)));
typedef float f32x16 __attribute__((ext_vector_type(16)));

#define EMB   768
#define HEADS 8
#define DHEAD 96
#define BATCH 8
#define SEQ   1024
#define ROWS  (BATCH * SEQ)   // 8192
#define ACTN  ((size_t)ROWS * EMB)  // 6291456

__device__ __forceinline__ void load16_lds(const bf16_t* g, bf16_t* l) {
    __builtin_amdgcn_global_load_lds(
        (__attribute__((address_space(1))) unsigned int*)g,
        (__attribute__((address_space(3))) unsigned int*)l,
        16, 0, 0);
}

// ---------------------------------------------------------------- fused prep

__device__ __forceinline__ void tile_transpose(
    const float* __restrict__ in, bf16_t* __restrict__ out,
    int K, int N, int n0, int k0, float (*t)[33], int tx, int ty0)
{
#pragma unroll
    for (int i = 0; i < 4; i++) {
        int ty = ty0 + 8 * i;
        t[ty][tx] = in[(size_t)(k0 + ty) * N + n0 + tx];
    }
    __syncthreads();
#pragma unroll
    for (int i = 0; i < 4; i++) {
        int ty = ty0 + 8 * i;
        out[(size_t)(n0 + ty) * K + k0 + tx] = (bf16_t)t[tx][ty];
    }
}

__global__ __launch_bounds__(256) void prep_kernel(
    const float* __restrict__ x, bf16_t* __restrict__ xb,
    const float* __restrict__ w_qkvr, bf16_t* __restrict__ wqkvrT,
    const float* __restrict__ w_proj, bf16_t* __restrict__ wprojT,
    const float* __restrict__ w_ff1, bf16_t* __restrict__ wff1T,
    const float* __restrict__ w_ff2, bf16_t* __restrict__ wff2T)
{
    __shared__ float t[32][33];
    int id = blockIdx.x;
    if (id < 768) {                      // cvt x -> xb
        const int n4 = (int)(ACTN / 4);
        const int stride = 768 * 256;
        for (int i = id * 256 + threadIdx.x; i < n4; i += stride) {
            const float4 v = ((const float4*)x)[i];
            bf16x4 o;
            o[0] = (bf16_t)v.x; o[1] = (bf16_t)v.y;
            o[2] = (bf16_t)v.z; o[3] = (bf16_t)v.w;
            ((bf16x4*)xb)[i] = o;
        }
        return;
    }
    id -= 768;
    const int tx = threadIdx.x & 31, ty0 = threadIdx.x >> 5;
    if (id < 2304) {                     // qkvr permuted transpose
        const int n0 = (id % 96) * 32, k0 = (id / 96) * 32;
        const int which = n0 / 768, hd0 = n0 % 768;
#pragma unroll
        for (int i = 0; i < 4; i++) {
            int ty = ty0 + 8 * i;
            t[ty][tx] = w_qkvr[(size_t)(k0 + ty) * 3072 + (hd0 + tx) * 4 + which];
        }
        __syncthreads();
#pragma unroll
        for (int i = 0; i < 4; i++) {
            int ty = ty0 + 8 * i;
            wqkvrT[(size_t)(n0 + ty) * 768 + k0 + tx] = (bf16_t)t[tx][ty];
        }
        return;
    }
    id -= 2304;
    if (id < 576) {                      // w_proj [768][768]
        tile_transpose(w_proj, wprojT, 768, 768, (id % 24) * 32, (id / 24) * 32, t, tx, ty0);
        return;
    }
    id -= 576;
    if (id < 2304) {                     // w_ff1 [768][3072]
        tile_transpose(w_ff1, wff1T, 768, 3072, (id % 96) * 32, (id / 96) * 32, t, tx, ty0);
        return;
    }
    id -= 2304;
    {                                    // w_ff2 [3072][768]
        tile_transpose(w_ff2, wff2T, 3072, 768, (id % 24) * 32, (id / 24) * 32, t, tx, ty0);
    }
}

// ---------------------------------------------------------------- GEMM (bf16 MFMA 32x32x16)
// C[M,N] = A[M,K] @ BT[N,K]^T + bias. Tile 256(M)x128(N), BK=64, 512 thr =
// 8 waves as 4(M)x2(N); wave C = 64x64 = 2x2 subtiles of 32x32 (f32x16 acc).
// LDS per buffer (48KB): A k-major [u=8][row=256] 16B units, B [u=8][row=128].
// Frag (lane l): row/col = l&31, k-half = l>>5, 8 contiguous k -> b128 read
// at base + ks*stride + sub*512 (compile-time offsets, conflict-free).

enum { EPI_QKVR = 0, EPI_PROJ = 1, EPI_GELU = 2, EPI_FF2 = 3 };

#define VMW6 asm volatile("s_waitcnt vmcnt(6)" ::: "memory")
#define VMW0 asm volatile("s_waitcnt vmcnt(0)" ::: "memory")
#define VMNONE do {} while (0)

#define STAGE6(DB) do { \
    bf16_t* db_ = lds + (DB) * 24576; \
    _Pragma("unroll") for (int i2 = 0; i2 < 4; i2++) { load16_lds(pa[i2], db_ + lA[i2]); pa[i2] += 64; } \
    _Pragma("unroll") for (int i2 = 0; i2 < 2; i2++) { load16_lds(pb[i2], db_ + lB[i2]); pb[i2] += 64; } \
} while (0)

// two k-slices (KSA, KSB): 8 ds_read_b128 + optional stage + 8 MFMAs
#define HALF(KSA, KSB, LB, PRE) do { \
    bf16x8 aA0 = *(const bf16x8*)((LB) + abase + (KSA) * 8192); \
    bf16x8 aA1 = *(const bf16x8*)((LB) + abase + (KSA) * 8192 + 512); \
    bf16x8 bA0 = *(const bf16x8*)((LB) + bbase + (KSA) * 4096); \
    bf16x8 bA1 = *(const bf16x8*)((LB) + bbase + (KSA) * 4096 + 512); \
    bf16x8 aB0 = *(const bf16x8*)((LB) + abase + (KSB) * 8192); \
    bf16x8 aB1 = *(const bf16x8*)((LB) + abase + (KSB) * 8192 + 512); \
    bf16x8 bB0 = *(const bf16x8*)((LB) + bbase + (KSB) * 4096); \
    bf16x8 bB1 = *(const bf16x8*)((LB) + bbase + (KSB) * 4096 + 512); \
    PRE; \
    __builtin_amdgcn_s_setprio(1); \
    acc[0][0] = __builtin_amdgcn_mfma_f32_32x32x16_bf16(aA0, bA0, acc[0][0], 0, 0, 0); \
    acc[0][1] = __builtin_amdgcn_mfma_f32_32x32x16_bf16(aA0, bA1, acc[0][1], 0, 0, 0); \
    acc[1][0] = __builtin_amdgcn_mfma_f32_32x32x16_bf16(aA1, bA0, acc[1][0], 0, 0, 0); \
    acc[1][1] = __builtin_amdgcn_mfma_f32_32x32x16_bf16(aA1, bA1, acc[1][1], 0, 0, 0); \
    acc[0][0] = __builtin_amdgcn_mfma_f32_32x32x16_bf16(aB0, bB0, acc[0][0], 0, 0, 0); \
    acc[0][1] = __builtin_amdgcn_mfma_f32_32x32x16_bf16(aB0, bB1, acc[0][1], 0, 0, 0); \
    acc[1][0] = __builtin_amdgcn_mfma_f32_32x32x16_bf16(aB1, bB0, acc[1][0], 0, 0, 0); \
    acc[1][1] = __builtin_amdgcn_mfma_f32_32x32x16_bf16(aB1, bB1, acc[1][1], 0, 0, 0); \
    __builtin_amdgcn_s_setprio(0); \
} while (0)

#define TILE1(BUF, DOSTAGE, GATE, DOBAR) do { \
    const char* lb_ = (const char*)lds + (BUF) * 49152; \
    HALF(0, 1, lb_, if (DOSTAGE) STAGE6(((BUF) + 2) % 3)); \
    HALF(2, 3, lb_, VMNONE); \
    GATE; \
    if (DOBAR) { __builtin_amdgcn_sched_barrier(0); __builtin_amdgcn_s_barrier(); } \
} while (0)

template <int EPI, int KSTRIDE, int NKT, int NBX>
__global__ __launch_bounds__(512, 2) void gemm32_kernel(
    const bf16_t* __restrict__ A,    // [M,KSTRIDE]
    const bf16_t* __restrict__ BT,   // [N,KSTRIDE]
    const float* __restrict__ bias,  // [N] (EPI_QKVR: original qkvr order)
    bf16_t* __restrict__ qo, bf16_t* __restrict__ ko,
    bf16_t* __restrict__ vTo, bf16_t* __restrict__ ro,   // EPI_QKVR outputs
    const float* __restrict__ resid,                     // EPI_PROJ / EPI_FF2 residual
    float* __restrict__ outf,                            // EPI_PROJ / EPI_FF2 fp32 out
    bf16_t* __restrict__ outb)                           // EPI_GELU bf16 out
{
    __shared__ __align__(16) bf16_t lds[3 * 24576];  // 144 KiB

    const int tid  = threadIdx.x;
    const int wave = tid >> 6, lane = tid & 63;
    const int ln = lane & 31, hi = lane >> 5;
    const int wrow = (wave >> 1) * 64, wcol = (wave & 1) * 64;  // 4(M) x 2(N)

    // bijective XCD swizzle (gridDim.x % 8 == 0 for all launches)
    const int cpx  = gridDim.x >> 3;
    const int id   = blockIdx.x;
    const int wgid = (id & 7) * cpx + (id >> 3);
    const int bx = wgid % NBX, by = wgid / NBX;
    const int m0 = by * 256, n0 = bx * 128;

    // frag read base byte-offsets within one buffer (k-major layout):
    // A frag (sub, ks): abase + ks*8192 + sub*512   [u = ks*2+hi, row 16B]
    // B frag (sub, ks): bbase + ks*4096 + sub*512
    const int abase = (wrow + ln) * 16 + hi * 4096;
    const int bbase = 32768 + (wcol + ln) * 16 + hi * 2048;

    // staging maps (linear, no swizzle): A unit i -> row i&255, u=i>>8;
    // B unit i -> row i&127, u=i>>7. LDS dst = unit*16B (= k-major layout).
    const bf16_t* pa[4]; const bf16_t* pb[2];
    int lA[4], lB[2];
#pragma unroll
    for (int i = 0; i < 4; i++) {
        const int u = tid + 512 * i;
        pa[i] = A + (size_t)(m0 + (u & 255)) * KSTRIDE + (u >> 8) * 8;
        lA[i] = u * 8;
    }
#pragma unroll
    for (int i = 0; i < 2; i++) {
        const int u = tid + 512 * i;
        pb[i] = BT + (size_t)(n0 + (u & 127)) * KSTRIDE + (u >> 7) * 8;
        lB[i] = 16384 + u * 8;
    }

    f32x16 acc[2][2] = {};

    STAGE6(0); STAGE6(1);
    VMW6; __builtin_amdgcn_s_barrier();

#pragma unroll 1
    for (int tg = 0; tg < NKT / 3 - 1; ++tg) {
        TILE1(0, 1, VMW6, 1);
        TILE1(1, 1, VMW6, 1);
        TILE1(2, 1, VMW6, 1);
    }
    TILE1(0, 1, VMW6, 1);
    TILE1(1, 0, VMW0, 1);
    TILE1(2, 0, VMNONE, 0);

    // ---------------- epilogues
    // C layout (m74/m101): col = ln, row = (reg&3) + 8*(reg>>2) + 4*hi.
    // row = m0 + wrow + mb*32 + g*8 + hi*4 + rg ; col = n0 + wcol + nb*32 + ln
    if (EPI == EPI_QKVR) {
        const int whichb = bx / 6;
        if (whichb == 2) {
            // V: transpose store, packed over 4 consecutive seq positions.
#pragma unroll
            for (int mb = 0; mb < 2; mb++)
#pragma unroll
            for (int nb = 0; nb < 2; nb++) {
                const int hd   = (bx % 6) * 128 + wcol + nb * 32 + ln;
                const int head = hd / DHEAD, dd = hd % DHEAD;
                const float bv = bias[hd * 4 + 2];
#pragma unroll
                for (int g = 0; g < 4; g++) {
                    const int row0 = m0 + wrow + mb * 32 + g * 8 + hi * 4;
                    const int b = row0 >> 10, nn0 = row0 & 1023;
                    bf16x4 w;
#pragma unroll
                    for (int rg = 0; rg < 4; rg++)
                        w[rg] = (bf16_t)(acc[mb][nb][g * 4 + rg] + bv);
                    *reinterpret_cast<bf16x4*>(
                        vTo + ((size_t)(b * HEADS + head) * DHEAD + dd) * SEQ + nn0) = w;
                }
            }
        } else {
            bf16_t* dst = (whichb == 0) ? qo : (whichb == 1) ? ko : ro;
#pragma unroll
            for (int mb = 0; mb < 2; mb++)
#pragma unroll
            for (int nb = 0; nb < 2; nb++) {
                const int hd   = (bx % 6) * 128 + wcol + nb * 32 + ln;
                const int head = hd / DHEAD, dd = hd % DHEAD;
                const float bv = bias[hd * 4 + whichb];
#pragma unroll
                for (int g = 0; g < 4; g++) {
#pragma unroll
                    for (int rg = 0; rg < 4; rg++) {
                        const int row = m0 + wrow + mb * 32 + g * 8 + hi * 4 + rg;
                        const int b = row >> 10, nn = row & 1023;
                        dst[((size_t)(b * HEADS + head) * SEQ + nn) * DHEAD + dd] =
                            (bf16_t)(acc[mb][nb][g * 4 + rg] + bv);
                    }
                }
            }
        }
    } else {
#pragma unroll
        for (int mb = 0; mb < 2; mb++)
#pragma unroll
        for (int nb = 0; nb < 2; nb++) {
            const int colg = n0 + wcol + nb * 32 + ln;
#pragma unroll
            for (int g = 0; g < 4; g++) {
#pragma unroll
                for (int rg = 0; rg < 4; rg++) {
                    const int row = m0 + wrow + mb * 32 + g * 8 + hi * 4 + rg;
                    float v = acc[mb][nb][g * 4 + rg] + bias[colg];
                    if (EPI == EPI_PROJ || EPI == EPI_FF2) {
                        outf[(size_t)row * EMB + colg] = v + resid[(size_t)row * EMB + colg];
                    } else {  // EPI_GELU: tanh-form gelu via sigmoid (|err|<3e-3 vs erf)
                        const float z = 1.5957691216057308f * v * (1.0f + 0.044715f * v * v);
                        const float gl = v / (1.0f + __expf(-z));
                        outb[(size_t)row * 3072 + colg] = (bf16_t)gl;
                    }
                }
            }
        }
    }
}

// ---------------------------------------------------------------- attention
// (unchanged — 4 blocks/CU co-residency is its latency hiding; do not
//  triple-buffer, that would drop occupancy 4 -> 1)

__global__ __launch_bounds__(256) void attn_kernel(
    const bf16_t* __restrict__ q, const bf16_t* __restrict__ k,
    const bf16_t* __restrict__ vT, const bf16_t* __restrict__ r,
    bf16_t* __restrict__ attn_out)
{
    __shared__ __align__(16) bf16_t Ks[64 * 96];
    __shared__ __align__(16) bf16_t Vs[96 * 64];
    __shared__ __align__(16) bf16_t P[4][16 * 72];

    const int tid = threadIdx.x, wave = tid >> 6, lane = tid & 63;
    const int quad = lane >> 4, col = lane & 15;
    const int bh = blockIdx.x & 63, qb = blockIdx.x >> 6;
    const int n0 = qb * 64 + wave * 16;
    const bf16_t* qp = q  + (size_t)bh * SEQ * DHEAD;
    const bf16_t* kb = k  + (size_t)bh * SEQ * DHEAD;
    const bf16_t* vb = vT + (size_t)bh * DHEAD * SEQ;
    bf16_t* Pw = P[wave];

    bf16x8 qf[3];
#pragma unroll
    for (int ks = 0; ks < 3; ks++)
        qf[ks] = *reinterpret_cast<const bf16x8*>(qp + (size_t)(n0 + col) * DHEAD + ks * 32 + quad * 8);

    const int u0 = tid, u1 = tid + 256, u2 = tid + 512;
    const int vf0 = u0 >> 3, vp0 = (u0 & 7) ^ (vf0 & 7);
    const int vf1 = u1 >> 3, vp1 = (u1 & 7) ^ (vf1 & 7);
    const int vf2 = u2 >> 3, vp2 = (u2 & 7) ^ (vf2 & 7);

    f32x4 O[6] = {};
    float lsum = 0.f;

    for (int ch = 0; ch < SEQ / 64; ch++) {
        const int kc0 = ch * 64;
        __syncthreads();
        const bf16_t* ksrc = kb + (size_t)kc0 * DHEAD;
        load16_lds(ksrc + u0 * 8, Ks + u0 * 8);
        load16_lds(ksrc + u1 * 8, Ks + u1 * 8);
        load16_lds(ksrc + u2 * 8, Ks + u2 * 8);
        load16_lds(vb + (size_t)vf0 * SEQ + kc0 + vp0 * 8, Vs + u0 * 8);
        load16_lds(vb + (size_t)vf1 * SEQ + kc0 + vp1 * 8, Vs + u1 * 8);
        load16_lds(vb + (size_t)vf2 * SEQ + kc0 + vp2 * 8, Vs + u2 * 8);
        __syncthreads();

        f32x4 s[4] = {};
#pragma unroll
        for (int ks = 0; ks < 3; ks++) {
#pragma unroll
            for (int h = 0; h < 4; h++) {
                bf16x8 kf = *reinterpret_cast<const bf16x8*>(Ks + (h * 16 + col) * DHEAD + ks * 32 + quad * 8);
                s[h] = __builtin_amdgcn_mfma_f32_16x16x32_bf16(kf, qf[ks], s[h], 0, 0, 0);
            }
        }
#pragma unroll
        for (int h = 0; h < 4; h++) {
            bf16x4 w;
#pragma unroll
            for (int rg = 0; rg < 4; rg++) {
                const float e = __expf(s[h][rg]);
                lsum += e;
                w[rg] = (bf16_t)e;
            }
            *reinterpret_cast<bf16x4*>(Pw + col * 72 + h * 16 + quad * 4) = w;
        }
        bf16x8 af0 = *reinterpret_cast<const bf16x8*>(Pw + col * 72 + quad * 8);
        bf16x8 af1 = *reinterpret_cast<const bf16x8*>(Pw + col * 72 + 32 + quad * 8);
#pragma unroll
        for (int tc = 0; tc < 6; tc++) {
            const int feat = tc * 16 + col;
            bf16x8 bv0 = *reinterpret_cast<const bf16x8*>(Vs + feat * 64 + ((quad)     ^ (col & 7)) * 8);
            bf16x8 bv1 = *reinterpret_cast<const bf16x8*>(Vs + feat * 64 + ((4 + quad) ^ (col & 7)) * 8);
            O[tc] = __builtin_amdgcn_mfma_f32_16x16x32_bf16(af0, bv0, O[tc], 0, 0, 0);
            O[tc] = __builtin_amdgcn_mfma_f32_16x16x32_bf16(af1, bv1, O[tc], 0, 0, 0);
        }
    }

    lsum += __shfl_xor(lsum, 16);
    lsum += __shfl_xor(lsum, 32);

    const float inv_sqrt_emb = 0.036084391824351615f;
    const int b = bh >> 3, h = bh & 7;
#pragma unroll
    for (int rg = 0; rg < 4; rg++) {
        const int nrow = quad * 4 + rg;
        const float lr = __shfl(lsum, nrow);
        const float scale = inv_sqrt_emb / lr;
        const int n = n0 + nrow;
#pragma unroll
        for (int tc = 0; tc < 6; tc++) {
            const int feat = tc * 16 + col;
            const float rv = (float)r[((size_t)bh * SEQ + n) * DHEAD + feat];
            attn_out[((size_t)(b * SEQ + n)) * EMB + h * DHEAD + feat] = (bf16_t)(O[tc][rg] * scale * rv);
        }
    }
}

// ---------------------------------------------------------------- LayerNorm (row=768)

__global__ __launch_bounds__(256) void ln_kernel(
    const float* __restrict__ in,
    const float* __restrict__ g, const float* __restrict__ b,
    float* __restrict__ y, bf16_t* __restrict__ yb)
{
    const int row = blockIdx.x * 4 + (threadIdx.x >> 6);
    const int lane = threadIdx.x & 63;
    const float4* rp = (const float4*)(in + (size_t)row * EMB);
    float4 v[3];
    float sum = 0.f;
#pragma unroll
    for (int i = 0; i < 3; i++) {
        float4 t = rp[lane + i * 64];
        v[i] = t;
        sum += t.x + t.y + t.z + t.w;
    }
#pragma unroll
    for (int off = 32; off; off >>= 1) sum += __shfl_xor(sum, off);
    const float mean = sum * (1.0f / 768.0f);
    float s2 = 0.f;
#pragma unroll
    for (int i = 0; i < 3; i++) {
        float dx = v[i].x - mean, dy = v[i].y - mean, dz = v[i].z - mean, dw = v[i].w - mean;
        s2 += dx * dx + dy * dy + dz * dz + dw * dw;
    }
#pragma unroll
    for (int off = 32; off; off >>= 1) s2 += __shfl_xor(s2, off);
    const float inv = rsqrtf(s2 * (1.0f / 768.0f) + 1e-5f);
    const float4* g4 = (const float4*)g;
    const float4* b4 = (const float4*)b;
#pragma unroll
    for (int i = 0; i < 3; i++) {
        const int c4 = lane + i * 64;
        const float4 gg = g4[c4], bb = b4[c4];
        float4 o;
        o.x = (v[i].x - mean) * inv * gg.x + bb.x;
        o.y = (v[i].y - mean) * inv * gg.y + bb.y;
        o.z = (v[i].z - mean) * inv * gg.z + bb.z;
        o.w = (v[i].w - mean) * inv * gg.w + bb.w;
        ((float4*)(y + (size_t)row * EMB))[c4] = o;
        if (yb) {
            bf16x4 ob;
            ob[0] = (bf16_t)o.x; ob[1] = (bf16_t)o.y; ob[2] = (bf16_t)o.z; ob[3] = (bf16_t)o.w;
            *reinterpret_cast<bf16x4*>(yb + (size_t)row * EMB + c4 * 4) = ob;
        }
    }
}

// ---------------------------------------------------------------- launch

extern "C" void kernel_launch(void* const* d_in, const int* in_sizes, int n_in,
                              void* d_out, int out_size, void* d_ws, size_t ws_size,
                              hipStream_t stream)
{
    const float* x      = (const float*)d_in[0];
    const float* w_qkvr = (const float*)d_in[1];
    const float* b_qkvr = (const float*)d_in[2];
    const float* w_proj = (const float*)d_in[3];
    const float* b_proj = (const float*)d_in[4];
    const float* ln1_g  = (const float*)d_in[5];
    const float* ln1_b  = (const float*)d_in[6];
    const float* w_ff1  = (const float*)d_in[7];
    const float* b_ff1  = (const float*)d_in[8];
    const float* w_ff2  = (const float*)d_in[9];
    const float* b_ff2  = (const float*)d_in[10];
    const float* ln2_g  = (const float*)d_in[11];
    const float* ln2_b  = (const float*)d_in[12];
    float* out = (float*)d_out;

    char* ws = (char*)d_ws;
    size_t off = 0;
    auto alloc = [&](size_t bytes) {
        char* p = ws + off;
        off += (bytes + 255) & ~(size_t)255;
        return (void*)p;
    };
    bf16_t* wqkvrT  = (bf16_t*)alloc((size_t)3072 * 768 * 2);
    bf16_t* wprojT  = (bf16_t*)alloc((size_t)768 * 768 * 2);
    bf16_t* wff1T   = (bf16_t*)alloc((size_t)3072 * 768 * 2);
    bf16_t* wff2T   = (bf16_t*)alloc((size_t)768 * 3072 * 2);
    float*  x1f     = (float*)alloc(ACTN * 4);
    bf16_t* x1b     = (bf16_t*)alloc(ACTN * 2);
    bf16_t* ff1     = (bf16_t*)alloc((size_t)ROWS * 3072 * 2);
    bf16_t* xb      = (bf16_t*)alloc(ACTN * 2);
    bf16_t* qbuf    = (bf16_t*)alloc(ACTN * 2);
    bf16_t* kbuf    = (bf16_t*)alloc(ACTN * 2);
    bf16_t* vTbuf   = (bf16_t*)alloc(ACTN * 2);
    bf16_t* rbuf    = (bf16_t*)alloc(ACTN * 2);
    bf16_t* attn_o  = (bf16_t*)alloc(ACTN * 2);
    float*  res     = out;  // d_out doubles as fp32 residual scratch

    // prep: cvt + all 4 weight transposes, one dispatch
    prep_kernel<<<8256, 256, 0, stream>>>(x, xb, w_qkvr, wqkvrT, w_proj, wprojT,
                                          w_ff1, wff1T, w_ff2, wff2T);

    // QKVR: M=8192, N=3072 -> 32 x 24 = 768 blocks (3 clean CU-rounds)
    gemm32_kernel<EPI_QKVR, 768, 12, 24><<<768, 512, 0, stream>>>(
        xb, wqkvrT, b_qkvr, qbuf, kbuf, vTbuf, rbuf, nullptr, nullptr, nullptr);

    attn_kernel<<<dim3(SEQ / 64 * BATCH * HEADS), 256, 0, stream>>>(qbuf, kbuf, vTbuf, rbuf, attn_o);

    // PROJ: M=8192, N=768 -> 32 x 6 = 192 blocks
    gemm32_kernel<EPI_PROJ, 768, 12, 6><<<192, 512, 0, stream>>>(
        attn_o, wprojT, b_proj, nullptr, nullptr, nullptr, nullptr, x, res, nullptr);
    ln_kernel<<<2048, 256, 0, stream>>>(res, ln1_g, ln1_b, x1f, x1b);

    // FF1+GELU: M=8192, N=3072
    gemm32_kernel<EPI_GELU, 768, 12, 24><<<768, 512, 0, stream>>>(
        x1b, wff1T, b_ff1, nullptr, nullptr, nullptr, nullptr, nullptr, nullptr, ff1);

    // FF2: M=8192, N=768, K=3072 (48 K-tiles, 192 blocks)
    gemm32_kernel<EPI_FF2, 3072, 48, 6><<<192, 512, 0, stream>>>(
        ff1, wff2T, b_ff2, nullptr, nullptr, nullptr, nullptr, x1f, res, nullptr);
    ln_kernel<<<2048, 256, 0, stream>>>(res, ln2_g, ln2_b, out, nullptr);

    (void)in_sizes; (void)n_in; (void)out_size; (void)ws_size;
}

// Round 9
// 343.559 us; speedup vs baseline: 1.4277x; 1.4277x over previous
//
#include <hip/hip_runtime.h>
#include <math.h>

// EncoderBlock: B=8, N=1024, EMB=768, HEADS=8, DHEAD=96
// R17 = R15 (best, 358.1us) + attention XCD-striped bh-major block swizzle.
//   R16 post-mortem: k-major LDS killed global_load_lds coalescing (lesson:
//   LDS layout choice == global access pattern choice; dst is unit*16B).
//   GEMM engine stays the R12/R15 16x16x32 single-barrier triple-buffer
//   (6 schedule variants all plateau ~615 TF == m233's 2-phase ceiling).
//   Attention: old order bh=id&63 put 64 different KV sets on consecutive
//   blocks -> 24.6MB live KV thrashing 8 non-coherent L2s. New mapping
//   bh=((id&7)<<3)|((id>>3)&7), qb=id>>6 gives XCD x the bh range
//   [8x,8x+8) = 3MB KV per XCD L2 -> each K/V fetched from HBM ~once.

typedef __bf16 bf16_t;
typedef __bf16 bf16x4 __attribute__((ext_vector_type(4)));
typedef __bf16 bf16x8 __attribute__((ext_vector_type(8)));
typedef float f32x4 __attribute__((ext_vector_type(4)));

#define EMB   768
#define HEADS 8
#define DHEAD 96
#define BATCH 8
#define SEQ   1024
#define ROWS  (BATCH * SEQ)   // 8192
#define ACTN  ((size_t)ROWS * EMB)  // 6291456

__device__ __forceinline__ void load16_lds(const bf16_t* g, bf16_t* l) {
    __builtin_amdgcn_global_load_lds(
        (__attribute__((address_space(1))) unsigned int*)g,
        (__attribute__((address_space(3))) unsigned int*)l,
        16, 0, 0);
}

// ---------------------------------------------------------------- fused prep

__device__ __forceinline__ void tile_transpose(
    const float* __restrict__ in, bf16_t* __restrict__ out,
    int K, int N, int n0, int k0, float (*t)[33], int tx, int ty0)
{
#pragma unroll
    for (int i = 0; i < 4; i++) {
        int ty = ty0 + 8 * i;
        t[ty][tx] = in[(size_t)(k0 + ty) * N + n0 + tx];
    }
    __syncthreads();
#pragma unroll
    for (int i = 0; i < 4; i++) {
        int ty = ty0 + 8 * i;
        out[(size_t)(n0 + ty) * K + k0 + tx] = (bf16_t)t[tx][ty];
    }
}

__global__ __launch_bounds__(256) void prep_kernel(
    const float* __restrict__ x, bf16_t* __restrict__ xb,
    const float* __restrict__ w_qkvr, bf16_t* __restrict__ wqkvrT,
    const float* __restrict__ w_proj, bf16_t* __restrict__ wprojT,
    const float* __restrict__ w_ff1, bf16_t* __restrict__ wff1T,
    const float* __restrict__ w_ff2, bf16_t* __restrict__ wff2T)
{
    __shared__ float t[32][33];
    int id = blockIdx.x;
    if (id < 768) {                      // cvt x -> xb
        const int n4 = (int)(ACTN / 4);
        const int stride = 768 * 256;
        for (int i = id * 256 + threadIdx.x; i < n4; i += stride) {
            const float4 v = ((const float4*)x)[i];
            bf16x4 o;
            o[0] = (bf16_t)v.x; o[1] = (bf16_t)v.y;
            o[2] = (bf16_t)v.z; o[3] = (bf16_t)v.w;
            ((bf16x4*)xb)[i] = o;
        }
        return;
    }
    id -= 768;
    const int tx = threadIdx.x & 31, ty0 = threadIdx.x >> 5;
    if (id < 2304) {                     // qkvr permuted transpose
        const int n0 = (id % 96) * 32, k0 = (id / 96) * 32;
        const int which = n0 / 768, hd0 = n0 % 768;
#pragma unroll
        for (int i = 0; i < 4; i++) {
            int ty = ty0 + 8 * i;
            t[ty][tx] = w_qkvr[(size_t)(k0 + ty) * 3072 + (hd0 + tx) * 4 + which];
        }
        __syncthreads();
#pragma unroll
        for (int i = 0; i < 4; i++) {
            int ty = ty0 + 8 * i;
            wqkvrT[(size_t)(n0 + ty) * 768 + k0 + tx] = (bf16_t)t[tx][ty];
        }
        return;
    }
    id -= 2304;
    if (id < 576) {                      // w_proj [768][768]
        tile_transpose(w_proj, wprojT, 768, 768, (id % 24) * 32, (id / 24) * 32, t, tx, ty0);
        return;
    }
    id -= 576;
    if (id < 2304) {                     // w_ff1 [768][3072]
        tile_transpose(w_ff1, wff1T, 768, 3072, (id % 96) * 32, (id / 96) * 32, t, tx, ty0);
        return;
    }
    id -= 2304;
    {                                    // w_ff2 [3072][768]
        tile_transpose(w_ff2, wff2T, 3072, 768, (id % 24) * 32, (id / 24) * 32, t, tx, ty0);
    }
}

// ---------------------------------------------------------------- GEMM (bf16 MFMA)
// R12 engine: 256(M)x128(N) tile, BK=64, 8 waves 4x2, triple-buffered LDS,
// single barrier + single counted vmcnt per K-tile.

enum { EPI_QKVR = 0, EPI_PROJ = 1, EPI_GELU = 2, EPI_FF2 = 3 };

#define VMW6 asm volatile("s_waitcnt vmcnt(6)" ::: "memory")
#define VMW0 asm volatile("s_waitcnt vmcnt(0)" ::: "memory")
#define VMNONE do {} while (0)

#define RD8(KC, LB) do { \
    _Pragma("unroll") for (int u = 0; u < 4; u++) { \
        af[u]  = *reinterpret_cast<const bf16x8*>((LB) + aoff[KC][u]); \
        bfr[u] = *reinterpret_cast<const bf16x8*>((LB) + boff[KC][u]); \
    } \
} while (0)

#define MM16() do { \
    __builtin_amdgcn_s_setprio(1); \
    _Pragma("unroll") for (int tr = 0; tr < 4; tr++) \
        _Pragma("unroll") for (int tc = 0; tc < 4; tc++) \
            acc[tr][tc] = __builtin_amdgcn_mfma_f32_16x16x32_bf16( \
                af[tr], bfr[tc], acc[tr][tc], 0, 0, 0); \
    __builtin_amdgcn_s_setprio(0); \
} while (0)

#define STAGE6(DB) do { \
    bf16_t* db_ = lds + (DB) * 24576; \
    _Pragma("unroll") for (int i2 = 0; i2 < 4; i2++) { load16_lds(pa[i2], db_ + lA[i2]); pa[i2] += 64; } \
    _Pragma("unroll") for (int i2 = 0; i2 < 2; i2++) { load16_lds(pb[i2], db_ + lB[i2]); pb[i2] += 64; } \
} while (0)

#define TILE1(BUF, DOSTAGE, GATE, DOBAR) do { \
    const char* lb_ = (const char*)lds + (BUF) * 49152; \
    bf16x8 af[4], bfr[4]; \
    RD8(0, lb_); \
    if (DOSTAGE) STAGE6(((BUF) + 2) % 3); \
    MM16(); \
    RD8(1, lb_); \
    MM16(); \
    GATE; \
    if (DOBAR) { __builtin_amdgcn_sched_barrier(0); __builtin_amdgcn_s_barrier(); } \
} while (0)

template <int EPI, int KSTRIDE, int NKT, int NBX>
__global__ __launch_bounds__(512, 2) void gemmsb_kernel(
    const bf16_t* __restrict__ A,    // [M,KSTRIDE]
    const bf16_t* __restrict__ BT,   // [N,KSTRIDE]
    const float* __restrict__ bias,  // [N] (EPI_QKVR: original qkvr order)
    bf16_t* __restrict__ qo, bf16_t* __restrict__ ko,
    bf16_t* __restrict__ vTo, bf16_t* __restrict__ ro,   // EPI_QKVR outputs
    const float* __restrict__ resid,                     // EPI_PROJ / EPI_FF2 residual
    float* __restrict__ outf,                            // EPI_PROJ / EPI_FF2 fp32 out
    bf16_t* __restrict__ outb)                           // EPI_GELU bf16 out
{
    __shared__ __align__(16) bf16_t lds[3 * 24576];  // 144 KiB

    const int tid  = threadIdx.x;
    const int wave = tid >> 6, lane = tid & 63;
    const int quad = lane >> 4, col16 = lane & 15;
    const int wrow = (wave >> 1) * 64, wcol = (wave & 1) * 64;  // 4(M) x 2(N)

    // bijective XCD swizzle (gridDim.x % 8 == 0 for all launches)
    const int cpx  = gridDim.x >> 3;
    const int id   = blockIdx.x;
    const int wgid = (id & 7) * cpx + (id >> 3);
    const int bx = wgid % NBX, by = wgid / NBX;
    const int m0 = by * 256, n0 = bx * 128;

    // -------- precomputed LDS read byte-offsets
    int aoff[2][4], boff[2][4];
#pragma unroll
    for (int kc = 0; kc < 2; kc++) {
#pragma unroll
        for (int u = 0; u < 4; u++) {
            const int R = wrow + u * 16 + col16;
            aoff[kc][u] = R * 128 + (((kc * 4 + quad) ^ (R & 7)) * 16);
            const int S = wcol + u * 16 + col16;
            boff[kc][u] = 32768 + S * 128 + (((kc * 4 + quad) ^ (S & 7)) * 16);
        }
    }

    // -------- staging maps (source pre-swizzled, LDS dst linear)
    const bf16_t* pa[4]; const bf16_t* pb[2];
    int lA[4], lB[2];
#pragma unroll
    for (int i = 0; i < 4; i++) {
        const int u = tid + 512 * i;
        const int r = u >> 3, j = (u & 7) ^ (r & 7);
        pa[i] = A + (size_t)(m0 + r) * KSTRIDE + j * 8;
        lA[i] = u * 8;
    }
#pragma unroll
    for (int i = 0; i < 2; i++) {
        const int u = tid + 512 * i;
        const int r = u >> 3, j = (u & 7) ^ (r & 7);
        pb[i] = BT + (size_t)(n0 + r) * KSTRIDE + j * 8;
        lB[i] = 16384 + u * 8;
    }

    f32x4 acc[4][4] = {};

    STAGE6(0); STAGE6(1);
    VMW6; __builtin_amdgcn_s_barrier();

#pragma unroll 1
    for (int tg = 0; tg < NKT / 3 - 1; ++tg) {
        TILE1(0, 1, VMW6, 1);
        TILE1(1, 1, VMW6, 1);
        TILE1(2, 1, VMW6, 1);
    }
    TILE1(0, 1, VMW6, 1);
    TILE1(1, 0, VMW0, 1);
    TILE1(2, 0, VMNONE, 0);

    // ---------------- epilogues
    if (EPI == EPI_QKVR) {
        const int whichb = bx / 6;
        if (whichb == 2) {
#pragma unroll
            for (int tr = 0; tr < 4; tr++) {
#pragma unroll
                for (int tc = 0; tc < 4; tc++) {
                    const int hd   = (bx % 6) * 128 + wcol + tc * 16 + col16;
                    const int head = hd / DHEAD, dd = hd % DHEAD;
                    const float bv = bias[hd * 4 + 2];
                    const int row0 = m0 + wrow + tr * 16 + quad * 4;
                    const int b = row0 >> 10, nn0 = row0 & 1023;
                    bf16x4 w;
#pragma unroll
                    for (int rg = 0; rg < 4; rg++) w[rg] = (bf16_t)(acc[tr][tc][rg] + bv);
                    *reinterpret_cast<bf16x4*>(
                        vTo + ((size_t)(b * HEADS + head) * DHEAD + dd) * SEQ + nn0) = w;
                }
            }
        } else {
            bf16_t* dst = (whichb == 0) ? qo : (whichb == 1) ? ko : ro;
#pragma unroll
            for (int tr = 0; tr < 4; tr++) {
#pragma unroll
                for (int tc = 0; tc < 4; tc++) {
                    const int hd   = (bx % 6) * 128 + wcol + tc * 16 + col16;
                    const int head = hd / DHEAD, dd = hd % DHEAD;
                    const float bv = bias[hd * 4 + whichb];
#pragma unroll
                    for (int rg = 0; rg < 4; rg++) {
                        const int row = m0 + wrow + tr * 16 + quad * 4 + rg;
                        const int b = row >> 10, nn = row & 1023;
                        dst[((size_t)(b * HEADS + head) * SEQ + nn) * DHEAD + dd] =
                            (bf16_t)(acc[tr][tc][rg] + bv);
                    }
                }
            }
        }
    } else {
#pragma unroll
        for (int tr = 0; tr < 4; tr++) {
#pragma unroll
            for (int tc = 0; tc < 4; tc++) {
#pragma unroll
                for (int rg = 0; rg < 4; rg++) {
                    const int row  = m0 + wrow + tr * 16 + quad * 4 + rg;
                    const int colg = n0 + wcol + tc * 16 + col16;
                    float v = acc[tr][tc][rg] + bias[colg];
                    if (EPI == EPI_PROJ || EPI == EPI_FF2) {
                        outf[(size_t)row * EMB + colg] = v + resid[(size_t)row * EMB + colg];
                    } else {  // EPI_GELU: tanh-form gelu via sigmoid (|err|<3e-3 vs erf)
                        const float z = 1.5957691216057308f * v * (1.0f + 0.044715f * v * v);
                        const float g = v / (1.0f + __expf(-z));
                        outb[(size_t)row * 3072 + colg] = (bf16_t)g;
                    }
                }
            }
        }
    }
}

// ---------------------------------------------------------------- attention
// XCD-striped bh-major swizzle: XCD x owns bh in [8x, 8x+8) -> 3MB KV per
// XCD L2 (fits 4MB); all 1024 blocks co-resident (4/CU) -> KV fetched ~once.

__global__ __launch_bounds__(256) void attn_kernel(
    const bf16_t* __restrict__ q, const bf16_t* __restrict__ k,
    const bf16_t* __restrict__ vT, const bf16_t* __restrict__ r,
    bf16_t* __restrict__ attn_out)
{
    __shared__ __align__(16) bf16_t Ks[64 * 96];
    __shared__ __align__(16) bf16_t Vs[96 * 64];
    __shared__ __align__(16) bf16_t P[4][16 * 72];

    const int tid = threadIdx.x, wave = tid >> 6, lane = tid & 63;
    const int quad = lane >> 4, col = lane & 15;
    const int id = blockIdx.x;
    const int bh = ((id & 7) << 3) | ((id >> 3) & 7);  // XCD-striped (bijective with qb)
    const int qb = id >> 6;
    const int n0 = qb * 64 + wave * 16;
    const bf16_t* qp = q  + (size_t)bh * SEQ * DHEAD;
    const bf16_t* kb = k  + (size_t)bh * SEQ * DHEAD;
    const bf16_t* vb = vT + (size_t)bh * DHEAD * SEQ;
    bf16_t* Pw = P[wave];

    bf16x8 qf[3];
#pragma unroll
    for (int ks = 0; ks < 3; ks++)
        qf[ks] = *reinterpret_cast<const bf16x8*>(qp + (size_t)(n0 + col) * DHEAD + ks * 32 + quad * 8);

    const int u0 = tid, u1 = tid + 256, u2 = tid + 512;
    const int vf0 = u0 >> 3, vp0 = (u0 & 7) ^ (vf0 & 7);
    const int vf1 = u1 >> 3, vp1 = (u1 & 7) ^ (vf1 & 7);
    const int vf2 = u2 >> 3, vp2 = (u2 & 7) ^ (vf2 & 7);

    f32x4 O[6] = {};
    float lsum = 0.f;

    for (int ch = 0; ch < SEQ / 64; ch++) {
        const int kc0 = ch * 64;
        __syncthreads();
        const bf16_t* ksrc = kb + (size_t)kc0 * DHEAD;
        load16_lds(ksrc + u0 * 8, Ks + u0 * 8);
        load16_lds(ksrc + u1 * 8, Ks + u1 * 8);
        load16_lds(ksrc + u2 * 8, Ks + u2 * 8);
        load16_lds(vb + (size_t)vf0 * SEQ + kc0 + vp0 * 8, Vs + u0 * 8);
        load16_lds(vb + (size_t)vf1 * SEQ + kc0 + vp1 * 8, Vs + u1 * 8);
        load16_lds(vb + (size_t)vf2 * SEQ + kc0 + vp2 * 8, Vs + u2 * 8);
        __syncthreads();

        f32x4 s[4] = {};
#pragma unroll
        for (int ks = 0; ks < 3; ks++) {
#pragma unroll
            for (int h = 0; h < 4; h++) {
                bf16x8 kf = *reinterpret_cast<const bf16x8*>(Ks + (h * 16 + col) * DHEAD + ks * 32 + quad * 8);
                s[h] = __builtin_amdgcn_mfma_f32_16x16x32_bf16(kf, qf[ks], s[h], 0, 0, 0);
            }
        }
#pragma unroll
        for (int h = 0; h < 4; h++) {
            bf16x4 w;
#pragma unroll
            for (int rg = 0; rg < 4; rg++) {
                const float e = __expf(s[h][rg]);
                lsum += e;
                w[rg] = (bf16_t)e;
            }
            *reinterpret_cast<bf16x4*>(Pw + col * 72 + h * 16 + quad * 4) = w;
        }
        bf16x8 af0 = *reinterpret_cast<const bf16x8*>(Pw + col * 72 + quad * 8);
        bf16x8 af1 = *reinterpret_cast<const bf16x8*>(Pw + col * 72 + 32 + quad * 8);
#pragma unroll
        for (int tc = 0; tc < 6; tc++) {
            const int feat = tc * 16 + col;
            bf16x8 bv0 = *reinterpret_cast<const bf16x8*>(Vs + feat * 64 + ((quad)     ^ (col & 7)) * 8);
            bf16x8 bv1 = *reinterpret_cast<const bf16x8*>(Vs + feat * 64 + ((4 + quad) ^ (col & 7)) * 8);
            O[tc] = __builtin_amdgcn_mfma_f32_16x16x32_bf16(af0, bv0, O[tc], 0, 0, 0);
            O[tc] = __builtin_amdgcn_mfma_f32_16x16x32_bf16(af1, bv1, O[tc], 0, 0, 0);
        }
    }

    lsum += __shfl_xor(lsum, 16);
    lsum += __shfl_xor(lsum, 32);

    const float inv_sqrt_emb = 0.036084391824351615f;
    const int b = bh >> 3, h = bh & 7;
#pragma unroll
    for (int rg = 0; rg < 4; rg++) {
        const int nrow = quad * 4 + rg;
        const float lr = __shfl(lsum, nrow);
        const float scale = inv_sqrt_emb / lr;
        const int n = n0 + nrow;
#pragma unroll
        for (int tc = 0; tc < 6; tc++) {
            const int feat = tc * 16 + col;
            const float rv = (float)r[((size_t)bh * SEQ + n) * DHEAD + feat];
            attn_out[((size_t)(b * SEQ + n)) * EMB + h * DHEAD + feat] = (bf16_t)(O[tc][rg] * scale * rv);
        }
    }
}

// ---------------------------------------------------------------- LayerNorm (row=768)

__global__ __launch_bounds__(256) void ln_kernel(
    const float* __restrict__ in,
    const float* __restrict__ g, const float* __restrict__ b,
    float* __restrict__ y, bf16_t* __restrict__ yb)
{
    const int row = blockIdx.x * 4 + (threadIdx.x >> 6);
    const int lane = threadIdx.x & 63;
    const float4* rp = (const float4*)(in + (size_t)row * EMB);
    float4 v[3];
    float sum = 0.f;
#pragma unroll
    for (int i = 0; i < 3; i++) {
        float4 t = rp[lane + i * 64];
        v[i] = t;
        sum += t.x + t.y + t.z + t.w;
    }
#pragma unroll
    for (int off = 32; off; off >>= 1) sum += __shfl_xor(sum, off);
    const float mean = sum * (1.0f / 768.0f);
    float s2 = 0.f;
#pragma unroll
    for (int i = 0; i < 3; i++) {
        float dx = v[i].x - mean, dy = v[i].y - mean, dz = v[i].z - mean, dw = v[i].w - mean;
        s2 += dx * dx + dy * dy + dz * dz + dw * dw;
    }
#pragma unroll
    for (int off = 32; off; off >>= 1) s2 += __shfl_xor(s2, off);
    const float inv = rsqrtf(s2 * (1.0f / 768.0f) + 1e-5f);
    const float4* g4 = (const float4*)g;
    const float4* b4 = (const float4*)b;
#pragma unroll
    for (int i = 0; i < 3; i++) {
        const int c4 = lane + i * 64;
        const float4 gg = g4[c4], bb = b4[c4];
        float4 o;
        o.x = (v[i].x - mean) * inv * gg.x + bb.x;
        o.y = (v[i].y - mean) * inv * gg.y + bb.y;
        o.z = (v[i].z - mean) * inv * gg.z + bb.z;
        o.w = (v[i].w - mean) * inv * gg.w + bb.w;
        ((float4*)(y + (size_t)row * EMB))[c4] = o;
        if (yb) {
            bf16x4 ob;
            ob[0] = (bf16_t)o.x; ob[1] = (bf16_t)o.y; ob[2] = (bf16_t)o.z; ob[3] = (bf16_t)o.w;
            *reinterpret_cast<bf16x4*>(yb + (size_t)row * EMB + c4 * 4) = ob;
        }
    }
}

// ---------------------------------------------------------------- launch

extern "C" void kernel_launch(void* const* d_in, const int* in_sizes, int n_in,
                              void* d_out, int out_size, void* d_ws, size_t ws_size,
                              hipStream_t stream)
{
    const float* x      = (const float*)d_in[0];
    const float* w_qkvr = (const float*)d_in[1];
    const float* b_qkvr = (const float*)d_in[2];
    const float* w_proj = (const float*)d_in[3];
    const float* b_proj = (const float*)d_in[4];
    const float* ln1_g  = (const float*)d_in[5];
    const float* ln1_b  = (const float*)d_in[6];
    const float* w_ff1  = (const float*)d_in[7];
    const float* b_ff1  = (const float*)d_in[8];
    const float* w_ff2  = (const float*)d_in[9];
    const float* b_ff2  = (const float*)d_in[10];
    const float* ln2_g  = (const float*)d_in[11];
    const float* ln2_b  = (const float*)d_in[12];
    float* out = (float*)d_out;

    char* ws = (char*)d_ws;
    size_t off = 0;
    auto alloc = [&](size_t bytes) {
        char* p = ws + off;
        off += (bytes + 255) & ~(size_t)255;
        return (void*)p;
    };
    bf16_t* wqkvrT  = (bf16_t*)alloc((size_t)3072 * 768 * 2);
    bf16_t* wprojT  = (bf16_t*)alloc((size_t)768 * 768 * 2);
    bf16_t* wff1T   = (bf16_t*)alloc((size_t)3072 * 768 * 2);
    bf16_t* wff2T   = (bf16_t*)alloc((size_t)768 * 3072 * 2);
    float*  x1f     = (float*)alloc(ACTN * 4);
    bf16_t* x1b     = (bf16_t*)alloc(ACTN * 2);
    bf16_t* ff1     = (bf16_t*)alloc((size_t)ROWS * 3072 * 2);
    bf16_t* xb      = (bf16_t*)alloc(ACTN * 2);
    bf16_t* qbuf    = (bf16_t*)alloc(ACTN * 2);
    bf16_t* kbuf    = (bf16_t*)alloc(ACTN * 2);
    bf16_t* vTbuf   = (bf16_t*)alloc(ACTN * 2);
    bf16_t* rbuf    = (bf16_t*)alloc(ACTN * 2);
    bf16_t* attn_o  = (bf16_t*)alloc(ACTN * 2);
    float*  res     = out;  // d_out doubles as fp32 residual scratch

    // prep: cvt + all 4 weight transposes, one dispatch
    prep_kernel<<<8256, 256, 0, stream>>>(x, xb, w_qkvr, wqkvrT, w_proj, wprojT,
                                          w_ff1, wff1T, w_ff2, wff2T);

    // QKVR: M=8192, N=3072 -> 32 x 24 = 768 blocks (3 clean CU-rounds)
    gemmsb_kernel<EPI_QKVR, 768, 12, 24><<<768, 512, 0, stream>>>(
        xb, wqkvrT, b_qkvr, qbuf, kbuf, vTbuf, rbuf, nullptr, nullptr, nullptr);

    attn_kernel<<<dim3(SEQ / 64 * BATCH * HEADS), 256, 0, stream>>>(qbuf, kbuf, vTbuf, rbuf, attn_o);

    // PROJ: M=8192, N=768 -> 32 x 6 = 192 blocks
    gemmsb_kernel<EPI_PROJ, 768, 12, 6><<<192, 512, 0, stream>>>(
        attn_o, wprojT, b_proj, nullptr, nullptr, nullptr, nullptr, x, res, nullptr);
    ln_kernel<<<2048, 256, 0, stream>>>(res, ln1_g, ln1_b, x1f, x1b);

    // FF1+GELU: M=8192, N=3072
    gemmsb_kernel<EPI_GELU, 768, 12, 24><<<768, 512, 0, stream>>>(
        x1b, wff1T, b_ff1, nullptr, nullptr, nullptr, nullptr, nullptr, nullptr, ff1);

    // FF2: M=8192, N=768, K=3072 (48 K-tiles, 192 blocks)
    gemmsb_kernel<EPI_FF2, 3072, 48, 6><<<192, 512, 0, stream>>>(
        ff1, wff2T, b_ff2, nullptr, nullptr, nullptr, nullptr, x1f, res, nullptr);
    ln_kernel<<<2048, 256, 0, stream>>>(res, ln2_g, ln2_b, out, nullptr);

    (void)in_sizes; (void)n_in; (void)out_size; (void)ws_size;
}

// Round 11
// 336.548 us; speedup vs baseline: 1.4574x; 1.0208x over previous
//
#include <hip/hip_runtime.h>
#include <math.h>

// EncoderBlock: B=8, N=1024, EMB=768, HEADS=8, DHEAD=96
// R19 = R18 resubmit (R10 bench died with the same container-infra error as
//       R5, which passed unchanged on resubmit). NW=3 path re-audited:
//       vmcnt(5) gating cannot deadlock (5-load waves exact, 6-load waves
//       over-wait by 1); tid<256 mask is wave-uniform (no divergent barrier);
//       B-tile bounds in range. No hang/fault hazard found.
//   R18 change vs R17 (343.6us best): BN=96 for the N=768 GEMMs ->
//   PROJ/FF2 run 256 blocks (full CU coverage, was 192 = 75%) at ZERO
//   extra HBM traffic. QKVR/FF1 stay BN=128. Engine/attn/prep/LN unchanged.

typedef __bf16 bf16_t;
typedef __bf16 bf16x4 __attribute__((ext_vector_type(4)));
typedef __bf16 bf16x8 __attribute__((ext_vector_type(8)));
typedef float f32x4 __attribute__((ext_vector_type(4)));

#define EMB   768
#define HEADS 8
#define DHEAD 96
#define BATCH 8
#define SEQ   1024
#define ROWS  (BATCH * SEQ)   // 8192
#define ACTN  ((size_t)ROWS * EMB)  // 6291456

__device__ __forceinline__ void load16_lds(const bf16_t* g, bf16_t* l) {
    __builtin_amdgcn_global_load_lds(
        (__attribute__((address_space(1))) unsigned int*)g,
        (__attribute__((address_space(3))) unsigned int*)l,
        16, 0, 0);
}

// ---------------------------------------------------------------- fused prep

__device__ __forceinline__ void tile_transpose(
    const float* __restrict__ in, bf16_t* __restrict__ out,
    int K, int N, int n0, int k0, float (*t)[33], int tx, int ty0)
{
#pragma unroll
    for (int i = 0; i < 4; i++) {
        int ty = ty0 + 8 * i;
        t[ty][tx] = in[(size_t)(k0 + ty) * N + n0 + tx];
    }
    __syncthreads();
#pragma unroll
    for (int i = 0; i < 4; i++) {
        int ty = ty0 + 8 * i;
        out[(size_t)(n0 + ty) * K + k0 + tx] = (bf16_t)t[tx][ty];
    }
}

__global__ __launch_bounds__(256) void prep_kernel(
    const float* __restrict__ x, bf16_t* __restrict__ xb,
    const float* __restrict__ w_qkvr, bf16_t* __restrict__ wqkvrT,
    const float* __restrict__ w_proj, bf16_t* __restrict__ wprojT,
    const float* __restrict__ w_ff1, bf16_t* __restrict__ wff1T,
    const float* __restrict__ w_ff2, bf16_t* __restrict__ wff2T)
{
    __shared__ float t[32][33];
    int id = blockIdx.x;
    if (id < 768) {                      // cvt x -> xb
        const int n4 = (int)(ACTN / 4);
        const int stride = 768 * 256;
        for (int i = id * 256 + threadIdx.x; i < n4; i += stride) {
            const float4 v = ((const float4*)x)[i];
            bf16x4 o;
            o[0] = (bf16_t)v.x; o[1] = (bf16_t)v.y;
            o[2] = (bf16_t)v.z; o[3] = (bf16_t)v.w;
            ((bf16x4*)xb)[i] = o;
        }
        return;
    }
    id -= 768;
    const int tx = threadIdx.x & 31, ty0 = threadIdx.x >> 5;
    if (id < 2304) {                     // qkvr permuted transpose
        const int n0 = (id % 96) * 32, k0 = (id / 96) * 32;
        const int which = n0 / 768, hd0 = n0 % 768;
#pragma unroll
        for (int i = 0; i < 4; i++) {
            int ty = ty0 + 8 * i;
            t[ty][tx] = w_qkvr[(size_t)(k0 + ty) * 3072 + (hd0 + tx) * 4 + which];
        }
        __syncthreads();
#pragma unroll
        for (int i = 0; i < 4; i++) {
            int ty = ty0 + 8 * i;
            wqkvrT[(size_t)(n0 + ty) * 768 + k0 + tx] = (bf16_t)t[tx][ty];
        }
        return;
    }
    id -= 2304;
    if (id < 576) {                      // w_proj [768][768]
        tile_transpose(w_proj, wprojT, 768, 768, (id % 24) * 32, (id / 24) * 32, t, tx, ty0);
        return;
    }
    id -= 576;
    if (id < 2304) {                     // w_ff1 [768][3072]
        tile_transpose(w_ff1, wff1T, 768, 3072, (id % 96) * 32, (id / 96) * 32, t, tx, ty0);
        return;
    }
    id -= 2304;
    {                                    // w_ff2 [3072][768]
        tile_transpose(w_ff2, wff2T, 3072, 768, (id % 24) * 32, (id / 24) * 32, t, tx, ty0);
    }
}

// ---------------------------------------------------------------- GEMM (bf16 MFMA)
// R12 engine: 256(M)xBN tile (BN = NW*32), BK=64, 8 waves 4(M)x2(N),
// triple-buffered LDS, single barrier + single counted vmcnt per K-tile.
// NW=4 -> BN=128 (2 full B-stage iters, gate vmcnt(6));
// NW=3 -> BN=96  (1.5 B-stage iters, 2nd masked tid<256, gate vmcnt(5)).

enum { EPI_QKVR = 0, EPI_PROJ = 1, EPI_GELU = 2, EPI_FF2 = 3 };

#define VMWG do { if (NW == 4) asm volatile("s_waitcnt vmcnt(6)" ::: "memory"); \
                  else         asm volatile("s_waitcnt vmcnt(5)" ::: "memory"); } while (0)
#define VMW0 asm volatile("s_waitcnt vmcnt(0)" ::: "memory")
#define VMNONE do {} while (0)

#define RDF(KC, LB) do { \
    _Pragma("unroll") for (int u = 0; u < 4; u++) \
        af[u]  = *reinterpret_cast<const bf16x8*>((LB) + aoff[KC][u]); \
    _Pragma("unroll") for (int u = 0; u < NW; u++) \
        bfr[u] = *reinterpret_cast<const bf16x8*>((LB) + boff[KC][u]); \
} while (0)

#define MMF() do { \
    __builtin_amdgcn_s_setprio(1); \
    _Pragma("unroll") for (int tr = 0; tr < 4; tr++) \
        _Pragma("unroll") for (int tc = 0; tc < NW; tc++) \
            acc[tr][tc] = __builtin_amdgcn_mfma_f32_16x16x32_bf16( \
                af[tr], bfr[tc], acc[tr][tc], 0, 0, 0); \
    __builtin_amdgcn_s_setprio(0); \
} while (0)

#define STAGEK(DB) do { \
    bf16_t* db_ = lds + (DB) * 24576; \
    _Pragma("unroll") for (int i2 = 0; i2 < 4; i2++) { load16_lds(pa[i2], db_ + lA[i2]); pa[i2] += 64; } \
    load16_lds(pb[0], db_ + lB[0]); pb[0] += 64; \
    if (NW == 4 || tid < 256) { load16_lds(pb[1], db_ + lB[1]); } \
    pb[1] += 64; \
} while (0)

#define TILE1(BUF, DOSTAGE, GATE, DOBAR) do { \
    const char* lb_ = (const char*)lds + (BUF) * 49152; \
    bf16x8 af[4], bfr[NW]; \
    RDF(0, lb_); \
    if (DOSTAGE) STAGEK(((BUF) + 2) % 3); \
    MMF(); \
    RDF(1, lb_); \
    MMF(); \
    GATE; \
    if (DOBAR) { __builtin_amdgcn_sched_barrier(0); __builtin_amdgcn_s_barrier(); } \
} while (0)

template <int EPI, int KSTRIDE, int NKT, int NBX, int NW>
__global__ __launch_bounds__(512, 2) void gemmsb_kernel(
    const bf16_t* __restrict__ A,    // [M,KSTRIDE]
    const bf16_t* __restrict__ BT,   // [N,KSTRIDE]
    const float* __restrict__ bias,  // [N] (EPI_QKVR: original qkvr order)
    bf16_t* __restrict__ qo, bf16_t* __restrict__ ko,
    bf16_t* __restrict__ vTo, bf16_t* __restrict__ ro,   // EPI_QKVR outputs
    const float* __restrict__ resid,                     // EPI_PROJ / EPI_FF2 residual
    float* __restrict__ outf,                            // EPI_PROJ / EPI_FF2 fp32 out
    bf16_t* __restrict__ outb)                           // EPI_GELU bf16 out
{
    __shared__ __align__(16) bf16_t lds[3 * 24576];  // 144 KiB

    const int tid  = threadIdx.x;
    const int wave = tid >> 6, lane = tid & 63;
    const int quad = lane >> 4, col16 = lane & 15;
    const int wrow = (wave >> 1) * 64;               // 4(M) waves
    const int wcol = (wave & 1) * (NW * 16);         // 2(N) waves

    // bijective XCD swizzle (gridDim.x % 8 == 0 for all launches)
    const int cpx  = gridDim.x >> 3;
    const int id   = blockIdx.x;
    const int wgid = (id & 7) * cpx + (id >> 3);
    const int bx = wgid % NBX, by = wgid / NBX;
    const int m0 = by * 256, n0 = bx * (NW * 32);

    // -------- precomputed LDS read byte-offsets
    int aoff[2][4], boff[2][NW];
#pragma unroll
    for (int kc = 0; kc < 2; kc++) {
#pragma unroll
        for (int u = 0; u < 4; u++) {
            const int R = wrow + u * 16 + col16;
            aoff[kc][u] = R * 128 + (((kc * 4 + quad) ^ (R & 7)) * 16);
        }
#pragma unroll
        for (int u = 0; u < NW; u++) {
            const int S = wcol + u * 16 + col16;
            boff[kc][u] = 32768 + S * 128 + (((kc * 4 + quad) ^ (S & 7)) * 16);
        }
    }

    // -------- staging maps (source pre-swizzled, LDS dst linear)
    // A: 2048 16B-units (4 iters); B: NW*256 units (2 iters, 2nd masked if NW=3)
    const bf16_t* pa[4]; const bf16_t* pb[2];
    int lA[4], lB[2];
#pragma unroll
    for (int i = 0; i < 4; i++) {
        const int u = tid + 512 * i;
        const int r = u >> 3, j = (u & 7) ^ (r & 7);
        pa[i] = A + (size_t)(m0 + r) * KSTRIDE + j * 8;
        lA[i] = u * 8;
    }
#pragma unroll
    for (int i = 0; i < 2; i++) {
        const int u = tid + 512 * i;
        const int r = u >> 3, j = (u & 7) ^ (r & 7);
        // NW=3: 2nd iter rows r in [96,128) are OOB -> never loaded (masked)
        pb[i] = BT + (size_t)(n0 + (r < NW * 32 ? r : 0)) * KSTRIDE + j * 8;
        lB[i] = 16384 + u * 8;
    }

    f32x4 acc[4][NW] = {};

    STAGEK(0); STAGEK(1);
    VMWG; __builtin_amdgcn_s_barrier();

#pragma unroll 1
    for (int tg = 0; tg < NKT / 3 - 1; ++tg) {
        TILE1(0, 1, VMWG, 1);
        TILE1(1, 1, VMWG, 1);
        TILE1(2, 1, VMWG, 1);
    }
    TILE1(0, 1, VMWG, 1);
    TILE1(1, 0, VMW0, 1);
    TILE1(2, 0, VMNONE, 0);

    // ---------------- epilogues
    if (EPI == EPI_QKVR) {               // only instantiated with NW=4 (BN=128)
        const int whichb = bx / 6;
        if (whichb == 2) {
#pragma unroll
            for (int tr = 0; tr < 4; tr++) {
#pragma unroll
                for (int tc = 0; tc < NW; tc++) {
                    const int hd   = (bx % 6) * 128 + wcol + tc * 16 + col16;
                    const int head = hd / DHEAD, dd = hd % DHEAD;
                    const float bv = bias[hd * 4 + 2];
                    const int row0 = m0 + wrow + tr * 16 + quad * 4;
                    const int b = row0 >> 10, nn0 = row0 & 1023;
                    bf16x4 w;
#pragma unroll
                    for (int rg = 0; rg < 4; rg++) w[rg] = (bf16_t)(acc[tr][tc][rg] + bv);
                    *reinterpret_cast<bf16x4*>(
                        vTo + ((size_t)(b * HEADS + head) * DHEAD + dd) * SEQ + nn0) = w;
                }
            }
        } else {
            bf16_t* dst = (whichb == 0) ? qo : (whichb == 1) ? ko : ro;
#pragma unroll
            for (int tr = 0; tr < 4; tr++) {
#pragma unroll
                for (int tc = 0; tc < NW; tc++) {
                    const int hd   = (bx % 6) * 128 + wcol + tc * 16 + col16;
                    const int head = hd / DHEAD, dd = hd % DHEAD;
                    const float bv = bias[hd * 4 + whichb];
#pragma unroll
                    for (int rg = 0; rg < 4; rg++) {
                        const int row = m0 + wrow + tr * 16 + quad * 4 + rg;
                        const int b = row >> 10, nn = row & 1023;
                        dst[((size_t)(b * HEADS + head) * SEQ + nn) * DHEAD + dd] =
                            (bf16_t)(acc[tr][tc][rg] + bv);
                    }
                }
            }
        }
    } else {
#pragma unroll
        for (int tr = 0; tr < 4; tr++) {
#pragma unroll
            for (int tc = 0; tc < NW; tc++) {
#pragma unroll
                for (int rg = 0; rg < 4; rg++) {
                    const int row  = m0 + wrow + tr * 16 + quad * 4 + rg;
                    const int colg = n0 + wcol + tc * 16 + col16;
                    float v = acc[tr][tc][rg] + bias[colg];
                    if (EPI == EPI_PROJ || EPI == EPI_FF2) {
                        outf[(size_t)row * EMB + colg] = v + resid[(size_t)row * EMB + colg];
                    } else {  // EPI_GELU: tanh-form gelu via sigmoid (|err|<3e-3 vs erf)
                        const float z = 1.5957691216057308f * v * (1.0f + 0.044715f * v * v);
                        const float g = v / (1.0f + __expf(-z));
                        outb[(size_t)row * 3072 + colg] = (bf16_t)g;
                    }
                }
            }
        }
    }
}

// ---------------------------------------------------------------- attention
// XCD-striped bh-major swizzle (R17): XCD x owns bh in [8x,8x+8) -> 3MB KV
// per XCD L2; KV fetched from HBM ~once.

__global__ __launch_bounds__(256) void attn_kernel(
    const bf16_t* __restrict__ q, const bf16_t* __restrict__ k,
    const bf16_t* __restrict__ vT, const bf16_t* __restrict__ r,
    bf16_t* __restrict__ attn_out)
{
    __shared__ __align__(16) bf16_t Ks[64 * 96];
    __shared__ __align__(16) bf16_t Vs[96 * 64];
    __shared__ __align__(16) bf16_t P[4][16 * 72];

    const int tid = threadIdx.x, wave = tid >> 6, lane = tid & 63;
    const int quad = lane >> 4, col = lane & 15;
    const int id = blockIdx.x;
    const int bh = ((id & 7) << 3) | ((id >> 3) & 7);  // XCD-striped (bijective with qb)
    const int qb = id >> 6;
    const int n0 = qb * 64 + wave * 16;
    const bf16_t* qp = q  + (size_t)bh * SEQ * DHEAD;
    const bf16_t* kb = k  + (size_t)bh * SEQ * DHEAD;
    const bf16_t* vb = vT + (size_t)bh * DHEAD * SEQ;
    bf16_t* Pw = P[wave];

    bf16x8 qf[3];
#pragma unroll
    for (int ks = 0; ks < 3; ks++)
        qf[ks] = *reinterpret_cast<const bf16x8*>(qp + (size_t)(n0 + col) * DHEAD + ks * 32 + quad * 8);

    const int u0 = tid, u1 = tid + 256, u2 = tid + 512;
    const int vf0 = u0 >> 3, vp0 = (u0 & 7) ^ (vf0 & 7);
    const int vf1 = u1 >> 3, vp1 = (u1 & 7) ^ (vf1 & 7);
    const int vf2 = u2 >> 3, vp2 = (u2 & 7) ^ (vf2 & 7);

    f32x4 O[6] = {};
    float lsum = 0.f;

    for (int ch = 0; ch < SEQ / 64; ch++) {
        const int kc0 = ch * 64;
        __syncthreads();
        const bf16_t* ksrc = kb + (size_t)kc0 * DHEAD;
        load16_lds(ksrc + u0 * 8, Ks + u0 * 8);
        load16_lds(ksrc + u1 * 8, Ks + u1 * 8);
        load16_lds(ksrc + u2 * 8, Ks + u2 * 8);
        load16_lds(vb + (size_t)vf0 * SEQ + kc0 + vp0 * 8, Vs + u0 * 8);
        load16_lds(vb + (size_t)vf1 * SEQ + kc0 + vp1 * 8, Vs + u1 * 8);
        load16_lds(vb + (size_t)vf2 * SEQ + kc0 + vp2 * 8, Vs + u2 * 8);
        __syncthreads();

        f32x4 s[4] = {};
#pragma unroll
        for (int ks = 0; ks < 3; ks++) {
#pragma unroll
            for (int h = 0; h < 4; h++) {
                bf16x8 kf = *reinterpret_cast<const bf16x8*>(Ks + (h * 16 + col) * DHEAD + ks * 32 + quad * 8);
                s[h] = __builtin_amdgcn_mfma_f32_16x16x32_bf16(kf, qf[ks], s[h], 0, 0, 0);
            }
        }
#pragma unroll
        for (int h = 0; h < 4; h++) {
            bf16x4 w;
#pragma unroll
            for (int rg = 0; rg < 4; rg++) {
                const float e = __expf(s[h][rg]);
                lsum += e;
                w[rg] = (bf16_t)e;
            }
            *reinterpret_cast<bf16x4*>(Pw + col * 72 + h * 16 + quad * 4) = w;
        }
        bf16x8 af0 = *reinterpret_cast<const bf16x8*>(Pw + col * 72 + quad * 8);
        bf16x8 af1 = *reinterpret_cast<const bf16x8*>(Pw + col * 72 + 32 + quad * 8);
#pragma unroll
        for (int tc = 0; tc < 6; tc++) {
            const int feat = tc * 16 + col;
            bf16x8 bv0 = *reinterpret_cast<const bf16x8*>(Vs + feat * 64 + ((quad)     ^ (col & 7)) * 8);
            bf16x8 bv1 = *reinterpret_cast<const bf16x8*>(Vs + feat * 64 + ((4 + quad) ^ (col & 7)) * 8);
            O[tc] = __builtin_amdgcn_mfma_f32_16x16x32_bf16(af0, bv0, O[tc], 0, 0, 0);
            O[tc] = __builtin_amdgcn_mfma_f32_16x16x32_bf16(af1, bv1, O[tc], 0, 0, 0);
        }
    }

    lsum += __shfl_xor(lsum, 16);
    lsum += __shfl_xor(lsum, 32);

    const float inv_sqrt_emb = 0.036084391824351615f;
    const int b = bh >> 3, h = bh & 7;
#pragma unroll
    for (int rg = 0; rg < 4; rg++) {
        const int nrow = quad * 4 + rg;
        const float lr = __shfl(lsum, nrow);
        const float scale = inv_sqrt_emb / lr;
        const int n = n0 + nrow;
#pragma unroll
        for (int tc = 0; tc < 6; tc++) {
            const int feat = tc * 16 + col;
            const float rv = (float)r[((size_t)bh * SEQ + n) * DHEAD + feat];
            attn_out[((size_t)(b * SEQ + n)) * EMB + h * DHEAD + feat] = (bf16_t)(O[tc][rg] * scale * rv);
        }
    }
}

// ---------------------------------------------------------------- LayerNorm (row=768)

__global__ __launch_bounds__(256) void ln_kernel(
    const float* __restrict__ in,
    const float* __restrict__ g, const float* __restrict__ b,
    float* __restrict__ y, bf16_t* __restrict__ yb)
{
    const int row = blockIdx.x * 4 + (threadIdx.x >> 6);
    const int lane = threadIdx.x & 63;
    const float4* rp = (const float4*)(in + (size_t)row * EMB);
    float4 v[3];
    float sum = 0.f;
#pragma unroll
    for (int i = 0; i < 3; i++) {
        float4 t = rp[lane + i * 64];
        v[i] = t;
        sum += t.x + t.y + t.z + t.w;
    }
#pragma unroll
    for (int off = 32; off; off >>= 1) sum += __shfl_xor(sum, off);
    const float mean = sum * (1.0f / 768.0f);
    float s2 = 0.f;
#pragma unroll
    for (int i = 0; i < 3; i++) {
        float dx = v[i].x - mean, dy = v[i].y - mean, dz = v[i].z - mean, dw = v[i].w - mean;
        s2 += dx * dx + dy * dy + dz * dz + dw * dw;
    }
#pragma unroll
    for (int off = 32; off; off >>= 1) s2 += __shfl_xor(s2, off);
    const float inv = rsqrtf(s2 * (1.0f / 768.0f) + 1e-5f);
    const float4* g4 = (const float4*)g;
    const float4* b4 = (const float4*)b;
#pragma unroll
    for (int i = 0; i < 3; i++) {
        const int c4 = lane + i * 64;
        const float4 gg = g4[c4], bb = b4[c4];
        float4 o;
        o.x = (v[i].x - mean) * inv * gg.x + bb.x;
        o.y = (v[i].y - mean) * inv * gg.y + bb.y;
        o.z = (v[i].z - mean) * inv * gg.z + bb.z;
        o.w = (v[i].w - mean) * inv * gg.w + bb.w;
        ((float4*)(y + (size_t)row * EMB))[c4] = o;
        if (yb) {
            bf16x4 ob;
            ob[0] = (bf16_t)o.x; ob[1] = (bf16_t)o.y; ob[2] = (bf16_t)o.z; ob[3] = (bf16_t)o.w;
            *reinterpret_cast<bf16x4*>(yb + (size_t)row * EMB + c4 * 4) = ob;
        }
    }
}

// ---------------------------------------------------------------- launch

extern "C" void kernel_launch(void* const* d_in, const int* in_sizes, int n_in,
                              void* d_out, int out_size, void* d_ws, size_t ws_size,
                              hipStream_t stream)
{
    const float* x      = (const float*)d_in[0];
    const float* w_qkvr = (const float*)d_in[1];
    const float* b_qkvr = (const float*)d_in[2];
    const float* w_proj = (const float*)d_in[3];
    const float* b_proj = (const float*)d_in[4];
    const float* ln1_g  = (const float*)d_in[5];
    const float* ln1_b  = (const float*)d_in[6];
    const float* w_ff1  = (const float*)d_in[7];
    const float* b_ff1  = (const float*)d_in[8];
    const float* w_ff2  = (const float*)d_in[9];
    const float* b_ff2  = (const float*)d_in[10];
    const float* ln2_g  = (const float*)d_in[11];
    const float* ln2_b  = (const float*)d_in[12];
    float* out = (float*)d_out;

    char* ws = (char*)d_ws;
    size_t off = 0;
    auto alloc = [&](size_t bytes) {
        char* p = ws + off;
        off += (bytes + 255) & ~(size_t)255;
        return (void*)p;
    };
    bf16_t* wqkvrT  = (bf16_t*)alloc((size_t)3072 * 768 * 2);
    bf16_t* wprojT  = (bf16_t*)alloc((size_t)768 * 768 * 2);
    bf16_t* wff1T   = (bf16_t*)alloc((size_t)3072 * 768 * 2);
    bf16_t* wff2T   = (bf16_t*)alloc((size_t)768 * 3072 * 2);
    float*  x1f     = (float*)alloc(ACTN * 4);
    bf16_t* x1b     = (bf16_t*)alloc(ACTN * 2);
    bf16_t* ff1     = (bf16_t*)alloc((size_t)ROWS * 3072 * 2);
    bf16_t* xb      = (bf16_t*)alloc(ACTN * 2);
    bf16_t* qbuf    = (bf16_t*)alloc(ACTN * 2);
    bf16_t* kbuf    = (bf16_t*)alloc(ACTN * 2);
    bf16_t* vTbuf   = (bf16_t*)alloc(ACTN * 2);
    bf16_t* rbuf    = (bf16_t*)alloc(ACTN * 2);
    bf16_t* attn_o  = (bf16_t*)alloc(ACTN * 2);
    float*  res     = out;  // d_out doubles as fp32 residual scratch

    // prep: cvt + all 4 weight transposes, one dispatch
    prep_kernel<<<8256, 256, 0, stream>>>(x, xb, w_qkvr, wqkvrT, w_proj, wprojT,
                                          w_ff1, wff1T, w_ff2, wff2T);

    // QKVR: M=8192, N=3072, BN=128 -> 32 x 24 = 768 blocks (3 clean rounds)
    gemmsb_kernel<EPI_QKVR, 768, 12, 24, 4><<<768, 512, 0, stream>>>(
        xb, wqkvrT, b_qkvr, qbuf, kbuf, vTbuf, rbuf, nullptr, nullptr, nullptr);

    attn_kernel<<<dim3(SEQ / 64 * BATCH * HEADS), 256, 0, stream>>>(qbuf, kbuf, vTbuf, rbuf, attn_o);

    // PROJ: M=8192, N=768, BN=96 -> 32 x 8 = 256 blocks (full CU coverage)
    gemmsb_kernel<EPI_PROJ, 768, 12, 8, 3><<<256, 512, 0, stream>>>(
        attn_o, wprojT, b_proj, nullptr, nullptr, nullptr, nullptr, x, res, nullptr);
    ln_kernel<<<2048, 256, 0, stream>>>(res, ln1_g, ln1_b, x1f, x1b);

    // FF1+GELU: M=8192, N=3072, BN=128 -> 768 blocks
    gemmsb_kernel<EPI_GELU, 768, 12, 24, 4><<<768, 512, 0, stream>>>(
        x1b, wff1T, b_ff1, nullptr, nullptr, nullptr, nullptr, nullptr, nullptr, ff1);

    // FF2: M=8192, N=768, K=3072, BN=96 -> 256 blocks (full CU coverage)
    gemmsb_kernel<EPI_FF2, 3072, 48, 8, 3><<<256, 512, 0, stream>>>(
        ff1, wff2T, b_ff2, nullptr, nullptr, nullptr, nullptr, x1f, res, nullptr);
    ln_kernel<<<2048, 256, 0, stream>>>(res, ln2_g, ln2_b, out, nullptr);

    (void)in_sizes; (void)n_in; (void)out_size; (void)ws_size;
}